// Round 9
// baseline (264.651 us; speedup 1.0000x reference)
//
#include <hip/hip_runtime.h>
#include <hip/hip_bf16.h>

// Problem constants: B=2, H=W=64, T=4096, C=192
#define BATCH 2
#define TLEN 4096
#define CC 192
#define PADC 2
#define APAD 40            // LDS row pitch in bf16 (32 data + 8 pad) -> 2-way banks
#define WPAD 265           // wkv LDS pitch (>=256, odd-ish for 2-way banks)

typedef __attribute__((ext_vector_type(8))) short bf16x8;
typedef __attribute__((ext_vector_type(4))) float f32x4;

__device__ __constant__ float PRF_X[16] = {-2,-2,-2,-2, -2,-1,0,1, 2,2,2,2, -1,0,1,2};
__device__ __constant__ float PRF_Y[16] = {-2,-1,0,1, 2,2,2,2, -1,0,1,2, -2,-2,-2,-2};

__device__ __forceinline__ unsigned short f2bf(float f) {
    unsigned u = __float_as_uint(f);
    u = (u + 0x7FFF + ((u >> 16) & 1)) >> 16;    // RNE
    return (unsigned short)u;
}
__device__ __forceinline__ float bf2f(unsigned short h) {
    return __uint_as_float(((unsigned)h) << 16);
}

// ---------------- split x -> bf16 hi/lo planes; zero the pad page ----------------
__global__ __launch_bounds__(256) void k_split_x(const float* __restrict__ x,
                                                 unsigned short* __restrict__ XH,
                                                 unsigned short* __restrict__ XL,
                                                 unsigned short* __restrict__ ZP) {
    if (blockIdx.x == 0 && threadIdx.x < 32) ZP[threadIdx.x] = 0;
    int idx = blockIdx.x * 256 + threadIdx.x;          // 4 elems each
    float4 v = *(const float4*)(x + (size_t)idx * 4);
    ushort4 hh, ll;
    float f, fh;
    f = v.x; hh.x = f2bf(f); fh = bf2f(hh.x); ll.x = f2bf(f - fh);
    f = v.y; hh.y = f2bf(f); fh = bf2f(hh.y); ll.y = f2bf(f - fh);
    f = v.z; hh.z = f2bf(f); fh = bf2f(hh.z); ll.z = f2bf(f - fh);
    f = v.w; hh.w = f2bf(f); fh = bf2f(hh.w); ll.w = f2bf(f - fh);
    *(ushort4*)(XH + (size_t)idx * 4) = hh;
    *(ushort4*)(XL + (size_t)idx * 4) = ll;
}

// ---------------- mix-scaled, TRANSPOSED weights WT[n][k], bf16 hi/lo ----------------
__global__ __launch_bounds__(256) void k_wcat_t(const float* __restrict__ Wk,
                                                const float* __restrict__ Wv,
                                                const float* __restrict__ Wr,
                                                const float* __restrict__ mk,
                                                const float* __restrict__ mv,
                                                const float* __restrict__ mr,
                                                unsigned short* __restrict__ WTH,
                                                unsigned short* __restrict__ WTL) {
    int idx = blockIdx.x * 256 + threadIdx.x;          // over 576*384
    int n = idx / 384, k = idx - n * 384;
    int sec = n / CC, nc = n - sec * CC;
    const float* W   = (sec == 0) ? Wk : (sec == 1) ? Wv : Wr;
    const float* mix = (sec == 0) ? mk : (sec == 1) ? mv : mr;
    float wv = (k < CC) ? mix[k] * W[k * CC + nc]
                        : (1.0f - mix[k - CC]) * W[(k - CC) * CC + nc];
    unsigned short h = f2bf(wv);
    WTH[idx] = h;
    WTL[idx] = f2bf(wv - bf2f(h));
}

// ---------------- WoT[n][k] bf16 hi/lo ----------------
__global__ __launch_bounds__(256) void k_prep_wo(const float* __restrict__ Wo,
                                                 unsigned short* __restrict__ WoTH,
                                                 unsigned short* __restrict__ WoTL) {
    int idx = blockIdx.x * 256 + threadIdx.x;          // over 192*192
    int n = idx / CC, k = idx - n * CC;
    float wv = Wo[k * CC + n];
    unsigned short h = f2bf(wv);
    WoTH[idx] = h;
    WoTL[idx] = f2bf(wv - bf2f(h));
}

// ---------------- GEMM1 (MFMA): Z = [x | qshift(x)] @ Wcat, bf16-split ----------------
// M=8192 N=576 K=384. 128 thr = 2 waves; tile 128x64; wave 64x64 = 4x4 frags.
// K-step 32, single-buffer LDS (padded rows), LDS-staged coalesced epilogue.
__global__ __launch_bounds__(128, 2) void k_gemm1_mfma(
        const unsigned short* __restrict__ XH, const unsigned short* __restrict__ XL,
        const unsigned short* __restrict__ WTH, const unsigned short* __restrict__ WTL,
        const unsigned short* __restrict__ ZP,
        float* __restrict__ ZTk, float* __restrict__ Zv, float* __restrict__ ZTr) {
    __shared__ __align__(16) char smem[34816];
    unsigned short* sAh = (unsigned short*)(smem);           // [128][APAD]
    unsigned short* sAl = (unsigned short*)(smem + 10240);
    unsigned short* sBh = (unsigned short*)(smem + 20480);   // [64][APAD]
    unsigned short* sBl = (unsigned short*)(smem + 25600);

    const int tid  = threadIdx.x;
    const int w    = tid >> 6;
    const int lane = tid & 63;
    const int bx = blockIdx.x;              // 0..8
    const int bm = blockIdx.y * 128;
    const int bn = bx * 64;
    const int lc  = tid & 3;                // chunk of 8 bf16
    const int ar0 = tid >> 2;               // 0..31

    f32x4 acc[4][4];
#pragma unroll
    for (int i = 0; i < 4; ++i)
#pragma unroll
        for (int j = 0; j < 4; ++j) acc[i][j] = f32x4{0.f, 0.f, 0.f, 0.f};

    uint4 rA[8], rB[4];

    auto loadA = [&](int step) {
        int k0 = step * 32;
#pragma unroll
        for (int q = 0; q < 4; ++q) {
            int rg = bm + ar0 + q * 32;
            const unsigned short *srcH, *srcL;
            if (k0 < CC) {
                size_t o = (size_t)rg * CC + k0 + lc * 8;
                srcH = XH + o; srcL = XL + o;
            } else {
                int c = k0 - CC + lc * 8;       // aligned 8-run stays in one group
                int g = c / 48;
                int t = rg & (TLEN - 1);
                int ri = t >> 6, rj = t & 63;
                int dr; bool ok;
                if      (g == 0) { dr = -1;  ok = (rj > 0);  }
                else if (g == 1) { dr =  1;  ok = (rj < 63); }
                else if (g == 2) { dr = -64; ok = (ri > 0);  }
                else             { dr =  64; ok = (ri < 63); }
                if (ok) { size_t o = (size_t)(rg + dr) * CC + c; srcH = XH + o; srcL = XL + o; }
                else    { srcH = ZP; srcL = ZP; }
            }
            rA[q * 2]     = *(const uint4*)srcH;
            rA[q * 2 + 1] = *(const uint4*)srcL;
        }
    };
    auto loadB = [&](int step) {
        int k0 = step * 32;
#pragma unroll
        for (int q = 0; q < 2; ++q) {
            size_t o = (size_t)(bn + ar0 + q * 32) * 384 + k0 + lc * 8;
            rB[q * 2]     = *(const uint4*)(WTH + o);
            rB[q * 2 + 1] = *(const uint4*)(WTL + o);
        }
    };
    auto writeS = [&]() {
#pragma unroll
        for (int q = 0; q < 4; ++q) {
            int off = (ar0 + q * 32) * APAD + lc * 8;
            *(uint4*)&sAh[off] = rA[q * 2];
            *(uint4*)&sAl[off] = rA[q * 2 + 1];
        }
#pragma unroll
        for (int q = 0; q < 2; ++q) {
            int off = (ar0 + q * 32) * APAD + lc * 8;
            *(uint4*)&sBh[off] = rB[q * 2];
            *(uint4*)&sBl[off] = rB[q * 2 + 1];
        }
    };

    const int r15 = lane & 15, ksub = lane >> 4;
    const int pc8 = ksub * 8;

    loadA(0); loadB(0);
    for (int step = 0; step < 12; ++step) {
        __syncthreads();                    // prior frag reads complete
        writeS();
        __syncthreads();                    // staged data visible
        if (step < 11) { loadA(step + 1); loadB(step + 1); }   // prefetch under MFMA
        bf16x8 ah[4], al[4], bh[4], bl[4];
#pragma unroll
        for (int f = 0; f < 4; ++f) {
            int ra = (w * 64 + f * 16 + r15) * APAD + pc8;
            ah[f] = *(const bf16x8*)&sAh[ra];
            al[f] = *(const bf16x8*)&sAl[ra];
            int rb = (f * 16 + r15) * APAD + pc8;
            bh[f] = *(const bf16x8*)&sBh[rb];
            bl[f] = *(const bf16x8*)&sBl[rb];
        }
#pragma unroll
        for (int fr = 0; fr < 4; ++fr)
#pragma unroll
            for (int fc = 0; fc < 4; ++fc) {
                acc[fr][fc] = __builtin_amdgcn_mfma_f32_16x16x32_bf16(ah[fr], bh[fc], acc[fr][fc], 0, 0, 0);
                acc[fr][fc] = __builtin_amdgcn_mfma_f32_16x16x32_bf16(ah[fr], bl[fc], acc[fr][fc], 0, 0, 0);
                acc[fr][fc] = __builtin_amdgcn_mfma_f32_16x16x32_bf16(al[fr], bh[fc], acc[fr][fc], 0, 0, 0);
            }
    }

    // ---- LDS-staged epilogue: per-instruction stores cover >=256B runs ----
    __syncthreads();                         // all frag reads done before overwrite
    float* T = (float*)smem + w * (64 * 68); // per-wave [64][68] f32
    const int sec   = bx / 3;                // 0=k 1=v 2=r
    const int cbase = (bx - sec * 3) * 64;

    if (sec == 1) {
        // stage row-major T[row][col]
#pragma unroll
        for (int fr = 0; fr < 4; ++fr)
#pragma unroll
            for (int fc = 0; fc < 4; ++fc) {
                int r0 = fr * 16 + ksub * 4, c = fc * 16 + r15;
                f32x4 v = acc[fr][fc];
                T[(r0 + 0) * 68 + c] = v[0];
                T[(r0 + 1) * 68 + c] = v[1];
                T[(r0 + 2) * 68 + c] = v[2];
                T[(r0 + 3) * 68 + c] = v[3];
            }
        __syncthreads();
#pragma unroll
        for (int it = 0; it < 16; ++it) {
            int row = it * 4 + ksub;
            float4 o = *(const float4*)&T[row * 68 + r15 * 4];
            *(float4*)(Zv + (size_t)(bm + w * 64 + row) * CC + cbase + r15 * 4) = o;
        }
    } else {
        // stage col-major T[col][row]; store transposed D[col][rows...]
        float* D = (sec == 0) ? ZTk : ZTr;
#pragma unroll
        for (int fr = 0; fr < 4; ++fr)
#pragma unroll
            for (int fc = 0; fc < 4; ++fc) {
                int r0 = fr * 16 + ksub * 4, c = fc * 16 + r15;
                *(f32x4*)&T[c * 68 + r0] = acc[fr][fc];
            }
        __syncthreads();
#pragma unroll
        for (int cg = 0; cg < 16; ++cg) {
            int c = cg * 4 + ksub;
            float4 o = *(const float4*)&T[c * 68 + r15 * 4];
            *(float4*)(D + (size_t)(cbase + c) * 8192 + bm + w * 64 + r15 * 4) = o;
        }
    }
}

// ---------------- GEMM2 (MFMA): out = P @ Wo, bf16-split, staged epilogue ------
__global__ __launch_bounds__(128, 2) void k_gemm2_mfma(
        const unsigned short* __restrict__ PH, const unsigned short* __restrict__ PL,
        const unsigned short* __restrict__ WoTH, const unsigned short* __restrict__ WoTL,
        float* __restrict__ out) {
    __shared__ __align__(16) char smem[34816];
    unsigned short* sAh = (unsigned short*)(smem);
    unsigned short* sAl = (unsigned short*)(smem + 10240);
    unsigned short* sBh = (unsigned short*)(smem + 20480);
    unsigned short* sBl = (unsigned short*)(smem + 25600);

    const int tid  = threadIdx.x;
    const int w    = tid >> 6;
    const int lane = tid & 63;
    const int bn = blockIdx.x * 64;
    const int bm = blockIdx.y * 128;
    const int lc  = tid & 3;
    const int ar0 = tid >> 2;

    f32x4 acc[4][4];
#pragma unroll
    for (int i = 0; i < 4; ++i)
#pragma unroll
        for (int j = 0; j < 4; ++j) acc[i][j] = f32x4{0.f, 0.f, 0.f, 0.f};

    uint4 rA[8], rB[4];
    auto loadAB = [&](int step) {
        int k0 = step * 32;
#pragma unroll
        for (int q = 0; q < 4; ++q) {
            size_t o = (size_t)(bm + ar0 + q * 32) * CC + k0 + lc * 8;
            rA[q * 2]     = *(const uint4*)(PH + o);
            rA[q * 2 + 1] = *(const uint4*)(PL + o);
        }
#pragma unroll
        for (int q = 0; q < 2; ++q) {
            size_t o = (size_t)(bn + ar0 + q * 32) * CC + k0 + lc * 8;
            rB[q * 2]     = *(const uint4*)(WoTH + o);
            rB[q * 2 + 1] = *(const uint4*)(WoTL + o);
        }
    };
    auto writeS = [&]() {
#pragma unroll
        for (int q = 0; q < 4; ++q) {
            int off = (ar0 + q * 32) * APAD + lc * 8;
            *(uint4*)&sAh[off] = rA[q * 2];
            *(uint4*)&sAl[off] = rA[q * 2 + 1];
        }
#pragma unroll
        for (int q = 0; q < 2; ++q) {
            int off = (ar0 + q * 32) * APAD + lc * 8;
            *(uint4*)&sBh[off] = rB[q * 2];
            *(uint4*)&sBl[off] = rB[q * 2 + 1];
        }
    };

    const int r15 = lane & 15, ksub = lane >> 4;
    const int pc8 = ksub * 8;

    loadAB(0);
    for (int step = 0; step < 6; ++step) {
        __syncthreads();
        writeS();
        __syncthreads();
        if (step < 5) loadAB(step + 1);
        bf16x8 ah[4], al[4], bh[4], bl[4];
#pragma unroll
        for (int f = 0; f < 4; ++f) {
            int ra = (w * 64 + f * 16 + r15) * APAD + pc8;
            ah[f] = *(const bf16x8*)&sAh[ra];
            al[f] = *(const bf16x8*)&sAl[ra];
            int rb = (f * 16 + r15) * APAD + pc8;
            bh[f] = *(const bf16x8*)&sBh[rb];
            bl[f] = *(const bf16x8*)&sBl[rb];
        }
#pragma unroll
        for (int fr = 0; fr < 4; ++fr)
#pragma unroll
            for (int fc = 0; fc < 4; ++fc) {
                acc[fr][fc] = __builtin_amdgcn_mfma_f32_16x16x32_bf16(ah[fr], bh[fc], acc[fr][fc], 0, 0, 0);
                acc[fr][fc] = __builtin_amdgcn_mfma_f32_16x16x32_bf16(ah[fr], bl[fc], acc[fr][fc], 0, 0, 0);
                acc[fr][fc] = __builtin_amdgcn_mfma_f32_16x16x32_bf16(al[fr], bh[fc], acc[fr][fc], 0, 0, 0);
            }
    }

    __syncthreads();
    float* T = (float*)smem + w * (64 * 68);
#pragma unroll
    for (int fr = 0; fr < 4; ++fr)
#pragma unroll
        for (int fc = 0; fc < 4; ++fc) {
            int r0 = fr * 16 + ksub * 4, c = fc * 16 + r15;
            f32x4 v = acc[fr][fc];
            T[(r0 + 0) * 68 + c] = v[0];
            T[(r0 + 1) * 68 + c] = v[1];
            T[(r0 + 2) * 68 + c] = v[2];
            T[(r0 + 3) * 68 + c] = v[3];
        }
    __syncthreads();
#pragma unroll
    for (int it = 0; it < 16; ++it) {
        int row = it * 4 + ksub;
        float4 o = *(const float4*)&T[row * 68 + r15 * 4];
        *(float4*)(out + (size_t)(bm + w * 64 + row) * CC + bn + r15 * 4) = o;
    }
}

// ---------------- fused band_est + ada_peak (RMW into pixel-major Zv) -------
__global__ __launch_bounds__(192) void k_bandpeak(const float* __restrict__ x,
                                                  const float* __restrict__ cvw,
                                                  const float* __restrict__ cvb,
                                                  const float* __restrict__ bns_v,
                                                  const float* __restrict__ bnb_v,
                                                  const float* __restrict__ chw,
                                                  const float* __restrict__ chb,
                                                  const float* __restrict__ bns_h,
                                                  const float* __restrict__ bnb_h,
                                                  float* __restrict__ Zv) {
    int pixg = blockIdx.x;
    int b   = pixg >> 12;
    int pix = pixg & 4095;
    int i = pix >> 6, j = pix & 63;
    int c = threadIdx.x;
    size_t xbase = (size_t)b * TLEN * CC;

    float sv0 = 0.f, sv1 = 0.f, sh0 = 0.f, sh1 = 0.f;
#pragma unroll
    for (int t = 0; t < 7; ++t) {
        int ii = i + t - 3;
        if (ii >= 0 && ii < 64) {
            float xv = x[xbase + (size_t)(ii * 64 + j) * CC + c];
            sv0 = fmaf(xv, cvw[(0 * CC + c) * 7 + t], sv0);
            sv1 = fmaf(xv, cvw[(1 * CC + c) * 7 + t], sv1);
        }
        int jj = j + t - 3;
        if (jj >= 0 && jj < 64) {
            float xh = x[xbase + (size_t)(i * 64 + jj) * CC + c];
            sh0 = fmaf(xh, chw[(0 * CC + c) * 7 + t], sh0);
            sh1 = fmaf(xh, chw[(1 * CC + c) * 7 + t], sh1);
        }
    }
    __shared__ float red[4][CC];
    __shared__ float gsh[4];
    red[0][c] = sv0; red[1][c] = sv1; red[2][c] = sh0; red[3][c] = sh1;
    __syncthreads();
    if (c < 64) {
#pragma unroll
        for (int r = 0; r < 4; ++r) {
            float v = red[r][c] + red[r][c + 64] + red[r][c + 128];
            v += __shfl_xor(v, 32);
            v += __shfl_xor(v, 16);
            v += __shfl_xor(v, 8);
            v += __shfl_xor(v, 4);
            v += __shfl_xor(v, 2);
            v += __shfl_xor(v, 1);
            if (c == 0) {
                const float inv = 0.9999950000374997f;    // 1/sqrt(1+1e-5)
                float bias, sc, sh;
                if (r < 2) { bias = cvb[r];     sc = bns_v[r];     sh = bnb_v[r]; }
                else       { bias = chb[r - 2]; sc = bns_h[r - 2]; sh = bnb_h[r - 2]; }
                float g = (v + bias) * (sc * inv) + sh;
                gsh[r] = 2.0f / (1.0f + expf(-g));        // sigmoid * (GB_MAX-1)
            }
        }
    }
    __syncthreads();

    __shared__ int   l_lt[16], l_rb[16];
    __shared__ float l_glt[16], l_grb[16];
    if (c < 16) {
        int n = c, blk = n >> 2;
        float mx = (blk == 0) ? -gsh[0] : (blk == 2) ? gsh[1] : 0.0f;
        float my = (blk == 1) ?  gsh[3] : (blk == 3) ? -gsh[2] : 0.0f;
        float px = (float)(i + PADC) + PRF_X[n] + mx;
        float py = (float)(j + PADC) + PRF_Y[n] + my;
        float flx = floorf(px), fly = floorf(py);
        float qltx = fminf(fmaxf(flx, 0.f), 67.f);
        float qlty = fminf(fmaxf(fly, 0.f), 67.f);
        float qrbx = fminf(fmaxf(flx + 1.f, 0.f), 67.f);
        float qrby = fminf(fmaxf(fly + 1.f, 0.f), 67.f);
        float pxc = fminf(fmaxf(px, 0.f), 67.f);
        float pyc = fminf(fmaxf(py, 0.f), 67.f);
        float glt = (1.f + (qltx - pxc)) * (1.f + (qlty - pyc));
        float grb = (1.f - (qrbx - pxc)) * (1.f - (qrby - pyc));
        int sltx = min(max((int)qltx - PADC, 0), 63);
        int slty = min(max((int)qlty - PADC, 0), 63);
        int srbx = min(max((int)qrbx - PADC, 0), 63);
        int srby = min(max((int)qrby - PADC, 0), 63);
        l_lt[n] = sltx * 64 + slty;
        l_rb[n] = srbx * 64 + srby;
        l_glt[n] = glt;
        l_grb[n] = grb;
    }
    __syncthreads();

    float acc = 0.f;
#pragma unroll
    for (int n = 0; n < 16; ++n) {
        acc = fmaf(l_glt[n], x[xbase + (size_t)l_lt[n] * CC + c], acc);
        acc = fmaf(l_grb[n], x[xbase + (size_t)l_rb[n] * CC + c], acc);
    }
    float peak = x[xbase + (size_t)pix * CC + c] - acc * 0.0625f;
    Zv[((size_t)b * TLEN + pix) * CC + c] += peak;
}

// ---------------- transpose v: Zv[8192][192] -> ZTv[192][8192] ----------------
__global__ __launch_bounds__(256) void k_transv(const float* __restrict__ Zv,
                                                float* __restrict__ ZTv) {
    __shared__ float tile[64][65];
    int tid = threadIdx.x;
    int rb = (blockIdx.x & 127) * 64;
    int cb = (blockIdx.x >> 7) * 64;
    int tr  = tid >> 4;
    int tc4 = (tid & 15) * 4;
#pragma unroll
    for (int q = 0; q < 4; ++q) {
        int r = tr + q * 16;
        float4 v = *(const float4*)(Zv + (size_t)(rb + r) * CC + cb + tc4);
        *(float4*)&tile[r][tc4] = v;
    }
    __syncthreads();
#pragma unroll
    for (int q = 0; q < 4; ++q) {
        int ccol = tr + q * 16;
        float4 o = {tile[tc4 + 0][ccol], tile[tc4 + 1][ccol],
                    tile[tc4 + 2][ccol], tile[tc4 + 3][ccol]};
        *(float4*)(ZTv + (size_t)(cb + ccol) * 8192 + rb + tc4) = o;
    }
}

// ---------------- transpose+split P: PT[192][8192] f32 -> PH/PL[8192][192] bf16 ----
__global__ __launch_bounds__(256) void k_transP(const float* __restrict__ PT,
                                                unsigned short* __restrict__ PH,
                                                unsigned short* __restrict__ PL) {
    __shared__ float tile[64][65];
    int tid = threadIdx.x;
    int mb = (blockIdx.x & 127) * 64;     // over 8192
    int cb = (blockIdx.x >> 7) * 64;      // over 192
    int tr  = tid >> 4;
    int tc4 = (tid & 15) * 4;
#pragma unroll
    for (int q = 0; q < 4; ++q) {
        int cr = tr + q * 16;
        float4 v = *(const float4*)(PT + (size_t)(cb + cr) * 8192 + mb + tc4);
        *(float4*)&tile[cr][tc4] = v;
    }
    __syncthreads();
#pragma unroll
    for (int q = 0; q < 4; ++q) {
        int m = tr + q * 16;
        ushort4 hh, ll;
        float f, fh;
        f = tile[tc4 + 0][m]; hh.x = f2bf(f); fh = bf2f(hh.x); ll.x = f2bf(f - fh);
        f = tile[tc4 + 1][m]; hh.y = f2bf(f); fh = bf2f(hh.y); ll.y = f2bf(f - fh);
        f = tile[tc4 + 2][m]; hh.z = f2bf(f); fh = bf2f(hh.z); ll.z = f2bf(f - fh);
        f = tile[tc4 + 3][m]; hh.w = f2bf(f); fh = bf2f(hh.w); ll.w = f2bf(f - fh);
        size_t o = (size_t)(mb + m) * CC + cb + tc4;
        *(ushort4*)(PH + o) = hh;
        *(ushort4*)(PL + o) = ll;
    }
}

// ---------------- bi_wkv: chunked associative scan, fully staged I/O -------
__global__ __launch_bounds__(256) void k_wkv2(const float* __restrict__ ZT,
                                              float* __restrict__ PT,
                                              const float* __restrict__ sd,
                                              const float* __restrict__ sf) {
    const int NTH = 256, CH = 16;
    int c = blockIdx.x % CC;
    int b = blockIdx.x / CC;
    const float w = sd[c] * (1.0f / 4096.0f);
    const float u = sf[c] * (1.0f / 4096.0f);

    __shared__ float buf[16 * WPAD];                 // staged plane (17 KB)
    __shared__ float s_m[NTH], s_a[NTH], s_b[NTH], s_L[NTH];

    int tid = threadIdx.x;
    size_t base = (size_t)c * 8192 + (size_t)b * TLEN;   // within each plane

    float kr[CH], vr[CH], rr[CH];

    auto coopLoad = [&](const float* src) {
#pragma unroll
        for (int i = 0; i < 4; ++i) {
            int g = i * 1024 + tid * 4;
            float4 v = *(const float4*)(src + g);
            int jj0 = g & 15;
            int tp  = g >> 4;
            buf[(jj0 + 0) * WPAD + tp] = v.x;
            buf[(jj0 + 1) * WPAD + tp] = v.y;
            buf[(jj0 + 2) * WPAD + tp] = v.z;
            buf[(jj0 + 3) * WPAD + tp] = v.w;
        }
    };
    auto chunkRead = [&](float* dst) {
#pragma unroll
        for (int jj = 0; jj < CH; ++jj) dst[jj] = buf[jj * WPAD + tid];
    };

    coopLoad(ZT + base);                                __syncthreads();
    chunkRead(kr);                                      __syncthreads();
    coopLoad(ZT + (size_t)CC * 8192 + base);            __syncthreads();
    chunkRead(vr);                                      __syncthreads();
    coopLoad(ZT + (size_t)2 * CC * 8192 + base);        __syncthreads();
    chunkRead(rr);                                      __syncthreads();

    // ---- forward local chunk summary
    float m = -1e38f, a = 0.f, bb = 0.f;
#pragma unroll
    for (int jj = 0; jj < CH; ++jj) {
        float kt = kr[jj], vt = vr[jj];
        float m2 = fmaxf(m - w, kt);
        float e1 = expf(m - w - m2);
        float e2 = expf(kt - m2);
        a = e1 * a + e2;
        bb = e1 * bb + e2 * vt;
        m = m2;
    }
    // ---- inclusive prefix scan of summaries
    s_m[tid] = m; s_a[tid] = a; s_b[tid] = bb; s_L[tid] = (float)CH;
    float L = (float)CH;
    for (int d = 1; d < NTH; d <<= 1) {
        __syncthreads();
        float pm = 0, pa = 0, pb = 0, pL = 0;
        bool has = (tid >= d);
        if (has) { pm = s_m[tid - d]; pa = s_a[tid - d]; pb = s_b[tid - d]; pL = s_L[tid - d]; }
        __syncthreads();
        if (has) {
            float pdec = pm - L * w;
            float m2 = fmaxf(pdec, m);
            float e1 = expf(pdec - m2);
            float e2 = expf(m - m2);
            a  = e1 * pa + e2 * a;
            bb = e1 * pb + e2 * bb;
            m = m2; L += pL;
            s_m[tid] = m; s_a[tid] = a; s_b[tid] = bb; s_L[tid] = L;
        }
    }
    __syncthreads();
    float fm = -1e38f, fa = 0.f, fb = 0.f;
    if (tid > 0) { fm = s_m[tid - 1]; fa = s_a[tid - 1]; fb = s_b[tid - 1]; }
    __syncthreads();

    // ---- backward local chunk summary
    m = -1e38f; a = 0.f; bb = 0.f;
#pragma unroll
    for (int jj = CH - 1; jj >= 0; --jj) {
        float kt = kr[jj], vt = vr[jj];
        float m2 = fmaxf(m - w, kt);
        float e1 = expf(m - w - m2);
        float e2 = expf(kt - m2);
        a = e1 * a + e2;
        bb = e1 * bb + e2 * vt;
        m = m2;
    }
    // ---- inclusive suffix scan
    s_m[tid] = m; s_a[tid] = a; s_b[tid] = bb; s_L[tid] = (float)CH;
    L = (float)CH;
    for (int d = 1; d < NTH; d <<= 1) {
        __syncthreads();
        float pm = 0, pa = 0, pb = 0, pL = 0;
        bool has = (tid + d) < NTH;
        if (has) { pm = s_m[tid + d]; pa = s_a[tid + d]; pb = s_b[tid + d]; pL = s_L[tid + d]; }
        __syncthreads();
        if (has) {
            float pdec = pm - L * w;
            float m2 = fmaxf(m, pdec);
            float e1 = expf(m - m2);
            float e2 = expf(pdec - m2);
            a  = e1 * a + e2 * pa;
            bb = e1 * bb + e2 * pb;
            m = m2; L += pL;
            s_m[tid] = m; s_a[tid] = a; s_b[tid] = bb; s_L[tid] = L;
        }
    }
    __syncthreads();
    float bm = -1e38f, ba = 0.f, bbv = 0.f;
    if (tid < NTH - 1) { bm = s_m[tid + 1]; ba = s_a[tid + 1]; bbv = s_b[tid + 1]; }
    __syncthreads();                                   // scan arrays free; buf reuse next

    // ---- backward re-scan: per-element backward states into registers
    float em[CH], ea[CH], eb[CH];
    m = bm; a = ba; bb = bbv;
#pragma unroll
    for (int jj = CH - 1; jj >= 0; --jj) {
        em[jj] = m; ea[jj] = a; eb[jj] = bb;
        float kt = kr[jj], vt = vr[jj];
        float m2 = fmaxf(m - w, kt);
        float e1 = expf(m - w - m2);
        float e2 = expf(kt - m2);
        a = e1 * a + e2;
        bb = e1 * bb + e2 * vt;
        m = m2;
    }

    // ---- forward re-scan + combine; y staged into buf, then coalesced store
    m = fm; a = fa; bb = fb;
#pragma unroll
    for (int jj = 0; jj < CH; ++jj) {
        float kt = kr[jj], vt = vr[jj];
        float ms = u + kt;
        float M = fmaxf(fmaxf(m, em[jj]), ms);
        float ef  = expf(m - M);
        float ebk = expf(em[jj] - M);
        float es  = expf(ms - M);
        float num = ef * bb + ebk * eb[jj] + es * vt;
        float den = ef * a + ebk * ea[jj] + es;
        float y = num / den;
        float sr = 1.0f / (1.0f + expf(-rr[jj]));
        buf[jj * WPAD + tid] = sr * y;
        float m2 = fmaxf(m - w, kt);
        float e1 = expf(m - w - m2);
        float e2 = expf(kt - m2);
        a = e1 * a + e2;
        bb = e1 * bb + e2 * vt;
        m = m2;
    }
    __syncthreads();
#pragma unroll
    for (int i = 0; i < 4; ++i) {
        int g = i * 1024 + tid * 4;
        int jj0 = g & 15;
        int tp  = g >> 4;
        float4 o = {buf[(jj0 + 0) * WPAD + tp], buf[(jj0 + 1) * WPAD + tp],
                    buf[(jj0 + 2) * WPAD + tp], buf[(jj0 + 3) * WPAD + tp]};
        *(float4*)(PT + base + g) = o;
    }
}

extern "C" void kernel_launch(void* const* d_in, const int* in_sizes, int n_in,
                              void* d_out, int out_size, void* d_ws, size_t ws_size,
                              hipStream_t stream) {
    const float* x     = (const float*)d_in[0];
    const float* mix_k = (const float*)d_in[3];
    const float* mix_v = (const float*)d_in[4];
    const float* mix_r = (const float*)d_in[5];
    const float* Wk    = (const float*)d_in[6];
    const float* Wv    = (const float*)d_in[7];
    const float* Wr    = (const float*)d_in[8];
    const float* Wo    = (const float*)d_in[9];
    const float* sd    = (const float*)d_in[10];
    const float* sf    = (const float*)d_in[11];
    const float* cvw   = (const float*)d_in[12];
    const float* cvb   = (const float*)d_in[13];
    const float* bns_v = (const float*)d_in[14];
    const float* bnb_v = (const float*)d_in[15];
    const float* chw   = (const float*)d_in[16];
    const float* chb   = (const float*)d_in[17];
    const float* bns_h = (const float*)d_in[18];
    const float* bnb_h = (const float*)d_in[19];
    float* out = (float*)d_out;
    char* W = (char*)d_ws;

    // byte-offset workspace plan (26.2 MB):
    float*          Zv   = (float*)(W + 0);                  // [8192][192] f32 (later PT)
    float*          ZTk  = (float*)(W + 6291456);            // ZT planes contiguous
    float*          ZTv  = (float*)(W + 12582912);
    float*          ZTr  = (float*)(W + 18874368);
    unsigned short* XH   = (unsigned short*)(W + 12582912);  // overlays ZTv until transv
    unsigned short* XL   = (unsigned short*)(W + 15728640);
    unsigned short* PH   = (unsigned short*)(W + 6291456);   // overlays ZTk after wkv2
    unsigned short* PL   = (unsigned short*)(W + 9437184);
    float*          PT   = Zv;                                // Zv dead after transv
    unsigned short* WTH  = (unsigned short*)(W + 25165824);
    unsigned short* WTL  = (unsigned short*)(W + 25608192);
    unsigned short* WoTH = (unsigned short*)(W + 26050560);
    unsigned short* WoTL = (unsigned short*)(W + 26124288);
    unsigned short* ZP   = (unsigned short*)(W + 26198016);

    k_split_x<<<1536, 256, 0, stream>>>(x, XH, XL, ZP);
    k_wcat_t<<<864, 256, 0, stream>>>(Wk, Wv, Wr, mix_k, mix_v, mix_r, WTH, WTL);
    k_prep_wo<<<144, 256, 0, stream>>>(Wo, WoTH, WoTL);
    k_gemm1_mfma<<<dim3(9, 64), 128, 0, stream>>>(XH, XL, WTH, WTL, ZP, ZTk, Zv, ZTr);
    k_bandpeak<<<8192, 192, 0, stream>>>(x, cvw, cvb, bns_v, bnb_v, chw, chb, bns_h, bnb_h, Zv);
    k_transv<<<384, 256, 0, stream>>>(Zv, ZTv);
    k_wkv2<<<384, 256, 0, stream>>>(ZTk, PT, sd, sf);
    k_transP<<<384, 256, 0, stream>>>(PT, PH, PL);
    k_gemm2_mfma<<<dim3(3, 64), 128, 0, stream>>>(PH, PL, WoTH, WoTL, out);
}

// Round 10
// 234.113 us; speedup vs baseline: 1.1304x; 1.1304x over previous
//
#include <hip/hip_runtime.h>
#include <hip/hip_bf16.h>

// Problem constants: B=2, H=W=64, T=4096, C=192
#define BATCH 2
#define TLEN 4096
#define CC 192
#define PADC 2
#define APAD 40            // LDS row pitch in bf16 (32 data + 8 pad) -> conflict-free b128 frags
#define WPAD 265           // wkv LDS pitch

typedef __attribute__((ext_vector_type(8))) short bf16x8;
typedef __attribute__((ext_vector_type(4))) float f32x4;

__device__ __constant__ float PRF_X[16] = {-2,-2,-2,-2, -2,-1,0,1, 2,2,2,2, -1,0,1,2};
__device__ __constant__ float PRF_Y[16] = {-2,-1,0,1, 2,2,2,2, -1,0,1,2, -2,-2,-2,-2};

__device__ __forceinline__ unsigned short f2bf(float f) {
    unsigned u = __float_as_uint(f);
    u = (u + 0x7FFF + ((u >> 16) & 1)) >> 16;    // RNE
    return (unsigned short)u;
}
__device__ __forceinline__ float bf2f(unsigned short h) {
    return __uint_as_float(((unsigned)h) << 16);
}

// ---------------- mix-scaled, TRANSPOSED weights WT[n][k], bf16 hi/lo ----------------
__global__ __launch_bounds__(256) void k_wcat_t(const float* __restrict__ Wk,
                                                const float* __restrict__ Wv,
                                                const float* __restrict__ Wr,
                                                const float* __restrict__ mk,
                                                const float* __restrict__ mv,
                                                const float* __restrict__ mr,
                                                unsigned short* __restrict__ WTH,
                                                unsigned short* __restrict__ WTL) {
    int idx = blockIdx.x * 256 + threadIdx.x;          // over 576*384
    int n = idx / 384, k = idx - n * 384;
    int sec = n / CC, nc = n - sec * CC;
    const float* W   = (sec == 0) ? Wk : (sec == 1) ? Wv : Wr;
    const float* mix = (sec == 0) ? mk : (sec == 1) ? mv : mr;
    float wv = (k < CC) ? mix[k] * W[k * CC + nc]
                        : (1.0f - mix[k - CC]) * W[(k - CC) * CC + nc];
    unsigned short h = f2bf(wv);
    WTH[idx] = h;
    WTL[idx] = f2bf(wv - bf2f(h));
}

// ---------------- WoT[n][k] bf16 hi/lo ----------------
__global__ __launch_bounds__(256) void k_prep_wo(const float* __restrict__ Wo,
                                                 unsigned short* __restrict__ WoTH,
                                                 unsigned short* __restrict__ WoTL) {
    int idx = blockIdx.x * 256 + threadIdx.x;          // over 192*192
    int n = idx / CC, k = idx - n * CC;
    float wv = Wo[k * CC + n];
    unsigned short h = f2bf(wv);
    WoTH[idx] = h;
    WoTL[idx] = f2bf(wv - bf2f(h));
}

// ---------------- GEMM1 (MFMA): Z = [x | qshift(x)] @ Wcat ----------------
// M=8192 N=576(=3x192) K=384. Grid (3 sections, 128 row-blocks), 256 thr = 4 waves
// (2x2), wave-tile 32x96 = 2x6 frags of 16x16x32. x read f32 and hi/lo-split
// in-register during staging; q_shift folded into the A-address.
__global__ __launch_bounds__(256, 2) void k_gemm1_mfma(
        const float* __restrict__ x,
        const unsigned short* __restrict__ WTH, const unsigned short* __restrict__ WTL,
        float* __restrict__ ZTk, float* __restrict__ Zv, float* __restrict__ ZTr) {
    __shared__ unsigned short sAh[64 * APAD], sAl[64 * APAD];
    __shared__ unsigned short sBh[192 * APAD], sBl[192 * APAD];
    const int tid  = threadIdx.x;
    const int w    = tid >> 6;
    const int lane = tid & 63;
    const int sec  = blockIdx.x;            // 0=k 1=v 2=r
    const int bm   = blockIdx.y * 64;

    // A-load geometry: 64 rows x 32 k, 8 f32 per thread
    const int arow = tid >> 2;              // 0..63
    const int akc  = (tid & 3) * 8;         // 0,8,16,24
    const int rg   = bm + arow;
    const int t    = rg & (TLEN - 1);
    const int ri   = t >> 6, rj = t & 63;

    f32x4 acc[2][6];
#pragma unroll
    for (int i = 0; i < 2; ++i)
#pragma unroll
        for (int j = 0; j < 6; ++j) acc[i][j] = f32x4{0.f, 0.f, 0.f, 0.f};

    float4 fA0, fA1;
    uint4 rB[6];

    auto loadA = [&](int k0) {
        bool aok;
        const float* src;
        if (k0 < CC) {
            src = x + (size_t)rg * CC + k0 + akc;
            aok = true;
        } else {
            int c = k0 - CC + akc;           // chunk of 8 stays in one 48-group
            int g = c / 48;
            int dr;
            if      (g == 0) { dr = -1;  aok = (rj > 0);  }
            else if (g == 1) { dr =  1;  aok = (rj < 63); }
            else if (g == 2) { dr = -64; aok = (ri > 0);  }
            else             { dr =  64; aok = (ri < 63); }
            src = x + (size_t)(rg + dr) * CC + c;
        }
        if (aok) { fA0 = *(const float4*)src; fA1 = *(const float4*)(src + 4); }
        else     { fA0 = make_float4(0.f,0.f,0.f,0.f); fA1 = fA0; }
    };
    auto loadB = [&](int k0) {
#pragma unroll
        for (int q = 0; q < 3; ++q) {
            int ch  = q * 256 + tid;         // 768 chunks: 192 cols x 4
            int col = ch >> 2, kc = (ch & 3) * 8;
            size_t o = (size_t)(sec * CC + col) * 384 + k0 + kc;
            rB[q * 2]     = *(const uint4*)(WTH + o);
            rB[q * 2 + 1] = *(const uint4*)(WTL + o);
        }
    };
    auto writeS = [&]() {
        float fa[8] = {fA0.x, fA0.y, fA0.z, fA0.w, fA1.x, fA1.y, fA1.z, fA1.w};
        unsigned hu[4], lu[4];
#pragma unroll
        for (int j = 0; j < 4; ++j) {
            unsigned short h0 = f2bf(fa[2*j]),   l0 = f2bf(fa[2*j]   - bf2f(h0));
            unsigned short h1 = f2bf(fa[2*j+1]), l1 = f2bf(fa[2*j+1] - bf2f(h1));
            hu[j] = (unsigned)h0 | ((unsigned)h1 << 16);
            lu[j] = (unsigned)l0 | ((unsigned)l1 << 16);
        }
        *(uint4*)&sAh[arow * APAD + akc] = make_uint4(hu[0], hu[1], hu[2], hu[3]);
        *(uint4*)&sAl[arow * APAD + akc] = make_uint4(lu[0], lu[1], lu[2], lu[3]);
#pragma unroll
        for (int q = 0; q < 3; ++q) {
            int ch  = q * 256 + tid;
            int col = ch >> 2, kc = (ch & 3) * 8;
            *(uint4*)&sBh[col * APAD + kc] = rB[q * 2];
            *(uint4*)&sBl[col * APAD + kc] = rB[q * 2 + 1];
        }
    };

    const int wrb = (w >> 1) * 32;           // wave row base
    const int wcb = (w & 1) * 96;            // wave col base
    const int r15 = lane & 15, ksub = lane >> 4;
    const int pc8 = ksub * 8;

    loadA(0); loadB(0);
    for (int step = 0; step < 12; ++step) {
        __syncthreads();                     // prior frag reads complete
        writeS();
        __syncthreads();                     // staged data visible
        if (step < 11) { loadA((step + 1) * 32); loadB((step + 1) * 32); }
        bf16x8 ah[2], al[2], bh[6], bl[6];
#pragma unroll
        for (int f = 0; f < 2; ++f) {
            int ra = (wrb + f * 16 + r15) * APAD + pc8;
            ah[f] = *(const bf16x8*)&sAh[ra];
            al[f] = *(const bf16x8*)&sAl[ra];
        }
#pragma unroll
        for (int f = 0; f < 6; ++f) {
            int rb = (wcb + f * 16 + r15) * APAD + pc8;
            bh[f] = *(const bf16x8*)&sBh[rb];
            bl[f] = *(const bf16x8*)&sBl[rb];
        }
#pragma unroll
        for (int fr = 0; fr < 2; ++fr)
#pragma unroll
            for (int fc = 0; fc < 6; ++fc) {
                acc[fr][fc] = __builtin_amdgcn_mfma_f32_16x16x32_bf16(ah[fr], bh[fc], acc[fr][fc], 0, 0, 0);
                acc[fr][fc] = __builtin_amdgcn_mfma_f32_16x16x32_bf16(ah[fr], bl[fc], acc[fr][fc], 0, 0, 0);
                acc[fr][fc] = __builtin_amdgcn_mfma_f32_16x16x32_bf16(al[fr], bh[fc], acc[fr][fc], 0, 0, 0);
            }
    }

    // ---- direct fragment epilogue (L2 absorbs scatter; round-6 evidence) ----
    if (sec == 1) {
#pragma unroll
        for (int fr = 0; fr < 2; ++fr)
#pragma unroll
            for (int fc = 0; fc < 6; ++fc) {
                int m0  = wrb + fr * 16 + ksub * 4;
                int col = wcb + fc * 16 + r15;
                f32x4 v = acc[fr][fc];
#pragma unroll
                for (int q = 0; q < 4; ++q)
                    Zv[(size_t)(bm + m0 + q) * CC + col] = v[q];
            }
    } else {
        float* D = (sec == 0) ? ZTk : ZTr;
#pragma unroll
        for (int fr = 0; fr < 2; ++fr)
#pragma unroll
            for (int fc = 0; fc < 6; ++fc) {
                int m0  = wrb + fr * 16 + ksub * 4;
                int col = wcb + fc * 16 + r15;
                f32x4 v = acc[fr][fc];
                *(float4*)(D + (size_t)col * 8192 + bm + m0) = make_float4(v[0], v[1], v[2], v[3]);
            }
    }
}

// ---------------- GEMM2 (MFMA): out = P @ Wo; A read straight from PT (f32) ----
// M=8192 N=192 K=192. Grid (3, 128): BM=64 BN=64; 256 thr = 4 waves (2x2),
// wave-tile 32x32 = 2x2 frags. Transpose+split folded into A-staging.
__global__ __launch_bounds__(256, 2) void k_gemm2_mfma(
        const float* __restrict__ PT,
        const unsigned short* __restrict__ WoTH, const unsigned short* __restrict__ WoTL,
        float* __restrict__ out) {
    __shared__ unsigned short sAh[64 * APAD], sAl[64 * APAD];
    __shared__ unsigned short sBh[64 * APAD], sBl[64 * APAD];
    const int tid  = threadIdx.x;
    const int w    = tid >> 6;
    const int lane = tid & 63;
    const int bn   = blockIdx.x * 64;
    const int bm   = blockIdx.y * 64;

    const int akk = tid >> 3;               // 0..31 (k row)
    const int am8 = (tid & 7) * 8;          // 0..56 (m chunk)
    const int bcol = tid >> 2;              // 0..63
    const int bkc  = (tid & 3) * 8;

    f32x4 acc[2][2];
#pragma unroll
    for (int i = 0; i < 2; ++i)
#pragma unroll
        for (int j = 0; j < 2; ++j) acc[i][j] = f32x4{0.f, 0.f, 0.f, 0.f};

    float4 p0, p1;
    uint4 rbh, rbl;
    auto loadAB = [&](int k0) {
        const float* pa = PT + (size_t)(k0 + akk) * 8192 + bm + am8;
        p0 = *(const float4*)pa;
        p1 = *(const float4*)(pa + 4);
        size_t o = (size_t)(bn + bcol) * CC + k0 + bkc;
        rbh = *(const uint4*)(WoTH + o);
        rbl = *(const uint4*)(WoTL + o);
    };
    auto writeS = [&]() {
        float fa[8] = {p0.x, p0.y, p0.z, p0.w, p1.x, p1.y, p1.z, p1.w};
#pragma unroll
        for (int j = 0; j < 8; ++j) {
            unsigned short h = f2bf(fa[j]);
            sAh[(am8 + j) * APAD + akk] = h;
            sAl[(am8 + j) * APAD + akk] = f2bf(fa[j] - bf2f(h));
        }
        *(uint4*)&sBh[bcol * APAD + bkc] = rbh;
        *(uint4*)&sBl[bcol * APAD + bkc] = rbl;
    };

    const int wrb = (w >> 1) * 32;
    const int wcb = (w & 1) * 32;
    const int r15 = lane & 15, ksub = lane >> 4;
    const int pc8 = ksub * 8;

    loadAB(0);
    for (int step = 0; step < 6; ++step) {
        __syncthreads();
        writeS();
        __syncthreads();
        if (step < 5) loadAB((step + 1) * 32);
        bf16x8 ah[2], al[2], bh[2], bl[2];
#pragma unroll
        for (int f = 0; f < 2; ++f) {
            int ra = (wrb + f * 16 + r15) * APAD + pc8;
            ah[f] = *(const bf16x8*)&sAh[ra];
            al[f] = *(const bf16x8*)&sAl[ra];
            int rb = (wcb + f * 16 + r15) * APAD + pc8;
            bh[f] = *(const bf16x8*)&sBh[rb];
            bl[f] = *(const bf16x8*)&sBl[rb];
        }
#pragma unroll
        for (int fr = 0; fr < 2; ++fr)
#pragma unroll
            for (int fc = 0; fc < 2; ++fc) {
                acc[fr][fc] = __builtin_amdgcn_mfma_f32_16x16x32_bf16(ah[fr], bh[fc], acc[fr][fc], 0, 0, 0);
                acc[fr][fc] = __builtin_amdgcn_mfma_f32_16x16x32_bf16(ah[fr], bl[fc], acc[fr][fc], 0, 0, 0);
                acc[fr][fc] = __builtin_amdgcn_mfma_f32_16x16x32_bf16(al[fr], bh[fc], acc[fr][fc], 0, 0, 0);
            }
    }

#pragma unroll
    for (int fr = 0; fr < 2; ++fr)
#pragma unroll
        for (int fc = 0; fc < 2; ++fc) {
            int m0  = wrb + fr * 16 + ksub * 4;
            int col = bn + wcb + fc * 16 + r15;
            f32x4 v = acc[fr][fc];
#pragma unroll
            for (int q = 0; q < 4; ++q)
                out[(size_t)(bm + m0 + q) * CC + col] = v[q];
        }
}

// ---------------- fused band_est + ada_peak (RMW into pixel-major Zv) -------
__global__ __launch_bounds__(192) void k_bandpeak(const float* __restrict__ x,
                                                  const float* __restrict__ cvw,
                                                  const float* __restrict__ cvb,
                                                  const float* __restrict__ bns_v,
                                                  const float* __restrict__ bnb_v,
                                                  const float* __restrict__ chw,
                                                  const float* __restrict__ chb,
                                                  const float* __restrict__ bns_h,
                                                  const float* __restrict__ bnb_h,
                                                  float* __restrict__ Zv) {
    int pixg = blockIdx.x;
    int b   = pixg >> 12;
    int pix = pixg & 4095;
    int i = pix >> 6, j = pix & 63;
    int c = threadIdx.x;
    size_t xbase = (size_t)b * TLEN * CC;

    float sv0 = 0.f, sv1 = 0.f, sh0 = 0.f, sh1 = 0.f;
#pragma unroll
    for (int t = 0; t < 7; ++t) {
        int ii = i + t - 3;
        if (ii >= 0 && ii < 64) {
            float xv = x[xbase + (size_t)(ii * 64 + j) * CC + c];
            sv0 = fmaf(xv, cvw[(0 * CC + c) * 7 + t], sv0);
            sv1 = fmaf(xv, cvw[(1 * CC + c) * 7 + t], sv1);
        }
        int jj = j + t - 3;
        if (jj >= 0 && jj < 64) {
            float xh = x[xbase + (size_t)(i * 64 + jj) * CC + c];
            sh0 = fmaf(xh, chw[(0 * CC + c) * 7 + t], sh0);
            sh1 = fmaf(xh, chw[(1 * CC + c) * 7 + t], sh1);
        }
    }
    __shared__ float red[4][CC];
    __shared__ float gsh[4];
    red[0][c] = sv0; red[1][c] = sv1; red[2][c] = sh0; red[3][c] = sh1;
    __syncthreads();
    if (c < 64) {
#pragma unroll
        for (int r = 0; r < 4; ++r) {
            float v = red[r][c] + red[r][c + 64] + red[r][c + 128];
            v += __shfl_xor(v, 32);
            v += __shfl_xor(v, 16);
            v += __shfl_xor(v, 8);
            v += __shfl_xor(v, 4);
            v += __shfl_xor(v, 2);
            v += __shfl_xor(v, 1);
            if (c == 0) {
                const float inv = 0.9999950000374997f;    // 1/sqrt(1+1e-5)
                float bias, sc, sh;
                if (r < 2) { bias = cvb[r];     sc = bns_v[r];     sh = bnb_v[r]; }
                else       { bias = chb[r - 2]; sc = bns_h[r - 2]; sh = bnb_h[r - 2]; }
                float g = (v + bias) * (sc * inv) + sh;
                gsh[r] = 2.0f / (1.0f + expf(-g));        // sigmoid * (GB_MAX-1)
            }
        }
    }
    __syncthreads();

    __shared__ int   l_lt[16], l_rb[16];
    __shared__ float l_glt[16], l_grb[16];
    if (c < 16) {
        int n = c, blk = n >> 2;
        float mx = (blk == 0) ? -gsh[0] : (blk == 2) ? gsh[1] : 0.0f;
        float my = (blk == 1) ?  gsh[3] : (blk == 3) ? -gsh[2] : 0.0f;
        float px = (float)(i + PADC) + PRF_X[n] + mx;
        float py = (float)(j + PADC) + PRF_Y[n] + my;
        float flx = floorf(px), fly = floorf(py);
        float qltx = fminf(fmaxf(flx, 0.f), 67.f);
        float qlty = fminf(fmaxf(fly, 0.f), 67.f);
        float qrbx = fminf(fmaxf(flx + 1.f, 0.f), 67.f);
        float qrby = fminf(fmaxf(fly + 1.f, 0.f), 67.f);
        float pxc = fminf(fmaxf(px, 0.f), 67.f);
        float pyc = fminf(fmaxf(py, 0.f), 67.f);
        float glt = (1.f + (qltx - pxc)) * (1.f + (qlty - pyc));
        float grb = (1.f - (qrbx - pxc)) * (1.f - (qrby - pyc));
        int sltx = min(max((int)qltx - PADC, 0), 63);
        int slty = min(max((int)qlty - PADC, 0), 63);
        int srbx = min(max((int)qrbx - PADC, 0), 63);
        int srby = min(max((int)qrby - PADC, 0), 63);
        l_lt[n] = sltx * 64 + slty;
        l_rb[n] = srbx * 64 + srby;
        l_glt[n] = glt;
        l_grb[n] = grb;
    }
    __syncthreads();

    float acc = 0.f;
#pragma unroll
    for (int n = 0; n < 16; ++n) {
        acc = fmaf(l_glt[n], x[xbase + (size_t)l_lt[n] * CC + c], acc);
        acc = fmaf(l_grb[n], x[xbase + (size_t)l_rb[n] * CC + c], acc);
    }
    float peak = x[xbase + (size_t)pix * CC + c] - acc * 0.0625f;
    Zv[((size_t)b * TLEN + pix) * CC + c] += peak;
}

// ---------------- transpose v: Zv[8192][192] -> ZTv[192][8192] ----------------
__global__ __launch_bounds__(256) void k_transv(const float* __restrict__ Zv,
                                                float* __restrict__ ZTv) {
    __shared__ float tile[64][65];
    int tid = threadIdx.x;
    int rb = (blockIdx.x & 127) * 64;
    int cb = (blockIdx.x >> 7) * 64;
    int tr  = tid >> 4;
    int tc4 = (tid & 15) * 4;
#pragma unroll
    for (int q = 0; q < 4; ++q) {
        int r = tr + q * 16;
        float4 v = *(const float4*)(Zv + (size_t)(rb + r) * CC + cb + tc4);
        *(float4*)&tile[r][tc4] = v;
    }
    __syncthreads();
#pragma unroll
    for (int q = 0; q < 4; ++q) {
        int ccol = tr + q * 16;
        float4 o = {tile[tc4 + 0][ccol], tile[tc4 + 1][ccol],
                    tile[tc4 + 2][ccol], tile[tc4 + 3][ccol]};
        *(float4*)(ZTv + (size_t)(cb + ccol) * 8192 + rb + tc4) = o;
    }
}

// ---------------- bi_wkv: chunked associative scan, fully staged I/O -------
__global__ __launch_bounds__(256) void k_wkv2(const float* __restrict__ ZT,
                                              float* __restrict__ PT,
                                              const float* __restrict__ sd,
                                              const float* __restrict__ sf) {
    const int NTH = 256, CH = 16;
    int c = blockIdx.x % CC;
    int b = blockIdx.x / CC;
    const float w = sd[c] * (1.0f / 4096.0f);
    const float u = sf[c] * (1.0f / 4096.0f);

    __shared__ float buf[16 * WPAD];
    __shared__ float s_m[NTH], s_a[NTH], s_b[NTH], s_L[NTH];

    int tid = threadIdx.x;
    size_t base = (size_t)c * 8192 + (size_t)b * TLEN;

    float kr[CH], vr[CH], rr[CH];

    auto coopLoad = [&](const float* src) {
#pragma unroll
        for (int i = 0; i < 4; ++i) {
            int g = i * 1024 + tid * 4;
            float4 v = *(const float4*)(src + g);
            int jj0 = g & 15;
            int tp  = g >> 4;
            buf[(jj0 + 0) * WPAD + tp] = v.x;
            buf[(jj0 + 1) * WPAD + tp] = v.y;
            buf[(jj0 + 2) * WPAD + tp] = v.z;
            buf[(jj0 + 3) * WPAD + tp] = v.w;
        }
    };
    auto chunkRead = [&](float* dst) {
#pragma unroll
        for (int jj = 0; jj < CH; ++jj) dst[jj] = buf[jj * WPAD + tid];
    };

    coopLoad(ZT + base);                                __syncthreads();
    chunkRead(kr);                                      __syncthreads();
    coopLoad(ZT + (size_t)CC * 8192 + base);            __syncthreads();
    chunkRead(vr);                                      __syncthreads();
    coopLoad(ZT + (size_t)2 * CC * 8192 + base);        __syncthreads();
    chunkRead(rr);                                      __syncthreads();

    // ---- forward local chunk summary
    float m = -1e38f, a = 0.f, bb = 0.f;
#pragma unroll
    for (int jj = 0; jj < CH; ++jj) {
        float kt = kr[jj], vt = vr[jj];
        float m2 = fmaxf(m - w, kt);
        float e1 = expf(m - w - m2);
        float e2 = expf(kt - m2);
        a = e1 * a + e2;
        bb = e1 * bb + e2 * vt;
        m = m2;
    }
    s_m[tid] = m; s_a[tid] = a; s_b[tid] = bb; s_L[tid] = (float)CH;
    float L = (float)CH;
    for (int d = 1; d < NTH; d <<= 1) {
        __syncthreads();
        float pm = 0, pa = 0, pb = 0, pL = 0;
        bool has = (tid >= d);
        if (has) { pm = s_m[tid - d]; pa = s_a[tid - d]; pb = s_b[tid - d]; pL = s_L[tid - d]; }
        __syncthreads();
        if (has) {
            float pdec = pm - L * w;
            float m2 = fmaxf(pdec, m);
            float e1 = expf(pdec - m2);
            float e2 = expf(m - m2);
            a  = e1 * pa + e2 * a;
            bb = e1 * pb + e2 * bb;
            m = m2; L += pL;
            s_m[tid] = m; s_a[tid] = a; s_b[tid] = bb; s_L[tid] = L;
        }
    }
    __syncthreads();
    float fm = -1e38f, fa = 0.f, fb = 0.f;
    if (tid > 0) { fm = s_m[tid - 1]; fa = s_a[tid - 1]; fb = s_b[tid - 1]; }
    __syncthreads();

    // ---- backward local chunk summary
    m = -1e38f; a = 0.f; bb = 0.f;
#pragma unroll
    for (int jj = CH - 1; jj >= 0; --jj) {
        float kt = kr[jj], vt = vr[jj];
        float m2 = fmaxf(m - w, kt);
        float e1 = expf(m - w - m2);
        float e2 = expf(kt - m2);
        a = e1 * a + e2;
        bb = e1 * bb + e2 * vt;
        m = m2;
    }
    s_m[tid] = m; s_a[tid] = a; s_b[tid] = bb; s_L[tid] = (float)CH;
    L = (float)CH;
    for (int d = 1; d < NTH; d <<= 1) {
        __syncthreads();
        float pm = 0, pa = 0, pb = 0, pL = 0;
        bool has = (tid + d) < NTH;
        if (has) { pm = s_m[tid + d]; pa = s_a[tid + d]; pb = s_b[tid + d]; pL = s_L[tid + d]; }
        __syncthreads();
        if (has) {
            float pdec = pm - L * w;
            float m2 = fmaxf(m, pdec);
            float e1 = expf(m - m2);
            float e2 = expf(pdec - m2);
            a  = e1 * a + e2 * pa;
            bb = e1 * bb + e2 * pb;
            m = m2; L += pL;
            s_m[tid] = m; s_a[tid] = a; s_b[tid] = bb; s_L[tid] = L;
        }
    }
    __syncthreads();
    float bm2 = -1e38f, ba = 0.f, bbv = 0.f;
    if (tid < NTH - 1) { bm2 = s_m[tid + 1]; ba = s_a[tid + 1]; bbv = s_b[tid + 1]; }
    __syncthreads();

    // ---- backward re-scan
    float em[CH], ea[CH], eb[CH];
    m = bm2; a = ba; bb = bbv;
#pragma unroll
    for (int jj = CH - 1; jj >= 0; --jj) {
        em[jj] = m; ea[jj] = a; eb[jj] = bb;
        float kt = kr[jj], vt = vr[jj];
        float m2 = fmaxf(m - w, kt);
        float e1 = expf(m - w - m2);
        float e2 = expf(kt - m2);
        a = e1 * a + e2;
        bb = e1 * bb + e2 * vt;
        m = m2;
    }

    // ---- forward re-scan + combine; y staged into buf, then coalesced store
    m = fm; a = fa; bb = fb;
#pragma unroll
    for (int jj = 0; jj < CH; ++jj) {
        float kt = kr[jj], vt = vr[jj];
        float ms = u + kt;
        float M = fmaxf(fmaxf(m, em[jj]), ms);
        float ef  = expf(m - M);
        float ebk = expf(em[jj] - M);
        float es  = expf(ms - M);
        float num = ef * bb + ebk * eb[jj] + es * vt;
        float den = ef * a + ebk * ea[jj] + es;
        float y = num / den;
        float sr = 1.0f / (1.0f + expf(-rr[jj]));
        buf[jj * WPAD + tid] = sr * y;
        float m2 = fmaxf(m - w, kt);
        float e1 = expf(m - w - m2);
        float e2 = expf(kt - m2);
        a = e1 * a + e2;
        bb = e1 * bb + e2 * vt;
        m = m2;
    }
    __syncthreads();
#pragma unroll
    for (int i = 0; i < 4; ++i) {
        int g = i * 1024 + tid * 4;
        int jj0 = g & 15;
        int tp  = g >> 4;
        float4 o = {buf[(jj0 + 0) * WPAD + tp], buf[(jj0 + 1) * WPAD + tp],
                    buf[(jj0 + 2) * WPAD + tp], buf[(jj0 + 3) * WPAD + tp]};
        *(float4*)(PT + base + g) = o;
    }
}

extern "C" void kernel_launch(void* const* d_in, const int* in_sizes, int n_in,
                              void* d_out, int out_size, void* d_ws, size_t ws_size,
                              hipStream_t stream) {
    const float* x     = (const float*)d_in[0];
    const float* mix_k = (const float*)d_in[3];
    const float* mix_v = (const float*)d_in[4];
    const float* mix_r = (const float*)d_in[5];
    const float* Wk    = (const float*)d_in[6];
    const float* Wv    = (const float*)d_in[7];
    const float* Wr    = (const float*)d_in[8];
    const float* Wo    = (const float*)d_in[9];
    const float* sd    = (const float*)d_in[10];
    const float* sf    = (const float*)d_in[11];
    const float* cvw   = (const float*)d_in[12];
    const float* cvb   = (const float*)d_in[13];
    const float* bns_v = (const float*)d_in[14];
    const float* bnb_v = (const float*)d_in[15];
    const float* chw   = (const float*)d_in[16];
    const float* chb   = (const float*)d_in[17];
    const float* bns_h = (const float*)d_in[18];
    const float* bnb_h = (const float*)d_in[19];
    float* out = (float*)d_out;
    char* W = (char*)d_ws;

    // byte-offset workspace plan (26.2 MB, previously proven available):
    float*          Zv   = (float*)(W + 0);            // [8192][192] f32 (later PT)
    float*          ZTk  = (float*)(W + 6291456);      // [192][8192] f32 planes
    float*          ZTv  = (float*)(W + 12582912);
    float*          ZTr  = (float*)(W + 18874368);
    float*          PT   = Zv;                          // Zv dead after transv
    unsigned short* WTH  = (unsigned short*)(W + 25165824);
    unsigned short* WTL  = (unsigned short*)(W + 25608192);
    unsigned short* WoTH = (unsigned short*)(W + 26050560);
    unsigned short* WoTL = (unsigned short*)(W + 26124288);

    k_wcat_t<<<864, 256, 0, stream>>>(Wk, Wv, Wr, mix_k, mix_v, mix_r, WTH, WTL);
    k_prep_wo<<<144, 256, 0, stream>>>(Wo, WoTH, WoTL);
    k_gemm1_mfma<<<dim3(3, 128), 256, 0, stream>>>(x, WTH, WTL, ZTk, Zv, ZTr);
    k_bandpeak<<<8192, 192, 0, stream>>>(x, cvw, cvb, bns_v, bnb_v, chw, chb, bns_h, bnb_h, Zv);
    k_transv<<<384, 256, 0, stream>>>(Zv, ZTv);
    k_wkv2<<<384, 256, 0, stream>>>(ZTk, PT, sd, sf);
    k_gemm2_mfma<<<dim3(3, 128), 256, 0, stream>>>(PT, WoTH, WoTL, out);
}

// Round 12
// 223.950 us; speedup vs baseline: 1.1817x; 1.0454x over previous
//
#include <hip/hip_runtime.h>
#include <hip/hip_bf16.h>

// Problem constants: B=2, H=W=64, T=4096, C=192
#define BATCH 2
#define TLEN 4096
#define CC 192
#define PADC 2
#define APAD 40            // LDS row pitch in bf16 (32 data + 8 pad)
#define WPAD 265           // wkv LDS pitch

typedef __attribute__((ext_vector_type(8))) short bf16x8;
typedef __attribute__((ext_vector_type(4))) float f32x4;

__device__ __constant__ float PRF_X[16] = {-2,-2,-2,-2, -2,-1,0,1, 2,2,2,2, -1,0,1,2};
__device__ __constant__ float PRF_Y[16] = {-2,-1,0,1, 2,2,2,2, -1,0,1,2, -2,-2,-2,-2};

__device__ __forceinline__ unsigned short f2bf(float f) {
    unsigned u = __float_as_uint(f);
    u = (u + 0x7FFF + ((u >> 16) & 1)) >> 16;    // RNE
    return (unsigned short)u;
}
__device__ __forceinline__ float bf2f(unsigned short h) {
    return __uint_as_float(((unsigned)h) << 16);
}

// ---------------- mix-scaled, TRANSPOSED weights WT[n][k], bf16 hi/lo ----------------
__global__ __launch_bounds__(256) void k_wcat_t(const float* __restrict__ Wk,
                                                const float* __restrict__ Wv,
                                                const float* __restrict__ Wr,
                                                const float* __restrict__ mk,
                                                const float* __restrict__ mv,
                                                const float* __restrict__ mr,
                                                unsigned short* __restrict__ WTH,
                                                unsigned short* __restrict__ WTL) {
    int idx = blockIdx.x * 256 + threadIdx.x;          // over 576*384
    int n = idx / 384, k = idx - n * 384;
    int sec = n / CC, nc = n - sec * CC;
    const float* W   = (sec == 0) ? Wk : (sec == 1) ? Wv : Wr;
    const float* mix = (sec == 0) ? mk : (sec == 1) ? mv : mr;
    float wv = (k < CC) ? mix[k] * W[k * CC + nc]
                        : (1.0f - mix[k - CC]) * W[(k - CC) * CC + nc];
    unsigned short h = f2bf(wv);
    WTH[idx] = h;
    WTL[idx] = f2bf(wv - bf2f(h));
}

// ---------------- WoT[n][k] bf16 hi/lo ----------------
__global__ __launch_bounds__(256) void k_prep_wo(const float* __restrict__ Wo,
                                                 unsigned short* __restrict__ WoTH,
                                                 unsigned short* __restrict__ WoTL) {
    int idx = blockIdx.x * 256 + threadIdx.x;          // over 192*192
    int n = idx / CC, k = idx - n * CC;
    float wv = Wo[k * CC + n];
    unsigned short h = f2bf(wv);
    WoTH[idx] = h;
    WoTL[idx] = f2bf(wv - bf2f(h));
}

// ---------------- GEMM1 (MFMA): Z = [x | qshift(x)] @ Wcat ----------------
// M=8192 N=576 K=384. Grid (6 half-sections, 128 row-blocks) = 768 blocks.
// BM=64 BN=96; 256 thr = 4 waves (2x2), wave-tile 32x48 = 2x3 frags.
// DOUBLE-BUFFERED LDS, one barrier per K-step; x split to bf16 hi/lo in-register.
__global__ __launch_bounds__(256, 2) void k_gemm1_mfma(
        const float* __restrict__ x,
        const unsigned short* __restrict__ WTH, const unsigned short* __restrict__ WTL,
        float* __restrict__ ZTk, float* __restrict__ Zv, float* __restrict__ ZTr) {
    __shared__ unsigned short sAh[2][64 * APAD], sAl[2][64 * APAD];
    __shared__ unsigned short sBh[2][96 * APAD], sBl[2][96 * APAD];
    const int tid  = threadIdx.x;
    const int w    = tid >> 6;
    const int lane = tid & 63;
    const int sec  = blockIdx.x >> 1;       // 0=k 1=v 2=r
    const int half = blockIdx.x & 1;        // 0/1: which 96-col half of the section
    const int bm   = blockIdx.y * 64;
    const int gcb  = sec * CC + half * 96;  // global WT col base

    // A-load geometry: 64 rows x 32 k, 8 f32 per thread
    const int arow = tid >> 2;              // 0..63
    const int akc  = (tid & 3) * 8;         // 0,8,16,24
    const int rg   = bm + arow;
    const int t    = rg & (TLEN - 1);
    const int ri   = t >> 6, rj = t & 63;

    f32x4 acc[2][3];
#pragma unroll
    for (int i = 0; i < 2; ++i)
#pragma unroll
        for (int j = 0; j < 3; ++j) acc[i][j] = f32x4{0.f, 0.f, 0.f, 0.f};

    float4 fA0, fA1;
    uint4 rB[4];

    auto loadA = [&](int k0) {
        bool aok;
        const float* src;
        if (k0 < CC) {
            src = x + (size_t)rg * CC + k0 + akc;
            aok = true;
        } else {
            int c = k0 - CC + akc;           // chunk of 8 stays in one 48-group
            int g = c / 48;
            int dr;
            if      (g == 0) { dr = -1;  aok = (rj > 0);  }
            else if (g == 1) { dr =  1;  aok = (rj < 63); }
            else if (g == 2) { dr = -64; aok = (ri > 0);  }
            else             { dr =  64; aok = (ri < 63); }
            src = x + (size_t)(rg + dr) * CC + c;
        }
        if (aok) { fA0 = *(const float4*)src; fA1 = *(const float4*)(src + 4); }
        else     { fA0 = make_float4(0.f,0.f,0.f,0.f); fA1 = fA0; }
    };
    auto loadB = [&](int k0) {
        {   // chunks 0..255: cols 0..63
            int col = tid >> 2, kc = (tid & 3) * 8;
            size_t o = (size_t)(gcb + col) * 384 + k0 + kc;
            rB[0] = *(const uint4*)(WTH + o);
            rB[1] = *(const uint4*)(WTL + o);
        }
        if (tid < 128) {    // chunks 256..383: cols 64..95
            int ch = 256 + tid;
            int col = ch >> 2, kc = (ch & 3) * 8;
            size_t o = (size_t)(gcb + col) * 384 + k0 + kc;
            rB[2] = *(const uint4*)(WTH + o);
            rB[3] = *(const uint4*)(WTL + o);
        }
    };
    auto writeS = [&](int buf) {
        float fa[8] = {fA0.x, fA0.y, fA0.z, fA0.w, fA1.x, fA1.y, fA1.z, fA1.w};
        unsigned hu[4], lu[4];
#pragma unroll
        for (int j = 0; j < 4; ++j) {
            unsigned short h0 = f2bf(fa[2*j]),   l0 = f2bf(fa[2*j]   - bf2f(h0));
            unsigned short h1 = f2bf(fa[2*j+1]), l1 = f2bf(fa[2*j+1] - bf2f(h1));
            hu[j] = (unsigned)h0 | ((unsigned)h1 << 16);
            lu[j] = (unsigned)l0 | ((unsigned)l1 << 16);
        }
        *(uint4*)&sAh[buf][arow * APAD + akc] = make_uint4(hu[0], hu[1], hu[2], hu[3]);
        *(uint4*)&sAl[buf][arow * APAD + akc] = make_uint4(lu[0], lu[1], lu[2], lu[3]);
        {
            int col = tid >> 2, kc = (tid & 3) * 8;
            *(uint4*)&sBh[buf][col * APAD + kc] = rB[0];
            *(uint4*)&sBl[buf][col * APAD + kc] = rB[1];
        }
        if (tid < 128) {
            int ch = 256 + tid;
            int col = ch >> 2, kc = (ch & 3) * 8;
            *(uint4*)&sBh[buf][col * APAD + kc] = rB[2];
            *(uint4*)&sBl[buf][col * APAD + kc] = rB[3];
        }
    };

    const int wrb = (w >> 1) * 32;           // wave row base
    const int wcb = (w & 1) * 48;            // wave col base
    const int r15 = lane & 15, ksub = lane >> 4;
    const int pc8 = ksub * 8;

    loadA(0); loadB(0);
    writeS(0);
    __syncthreads();

    int buf = 0;
    for (int step = 0; step < 12; ++step) {
        if (step < 11) { loadA((step + 1) * 32); loadB((step + 1) * 32); }
        bf16x8 ah[2], al[2], bh[3], bl[3];
#pragma unroll
        for (int f = 0; f < 2; ++f) {
            int ra = (wrb + f * 16 + r15) * APAD + pc8;
            ah[f] = *(const bf16x8*)&sAh[buf][ra];
            al[f] = *(const bf16x8*)&sAl[buf][ra];
        }
#pragma unroll
        for (int f = 0; f < 3; ++f) {
            int rb = (wcb + f * 16 + r15) * APAD + pc8;
            bh[f] = *(const bf16x8*)&sBh[buf][rb];
            bl[f] = *(const bf16x8*)&sBl[buf][rb];
        }
#pragma unroll
        for (int fr = 0; fr < 2; ++fr)
#pragma unroll
            for (int fc = 0; fc < 3; ++fc) {
                acc[fr][fc] = __builtin_amdgcn_mfma_f32_16x16x32_bf16(ah[fr], bh[fc], acc[fr][fc], 0, 0, 0);
                acc[fr][fc] = __builtin_amdgcn_mfma_f32_16x16x32_bf16(ah[fr], bl[fc], acc[fr][fc], 0, 0, 0);
                acc[fr][fc] = __builtin_amdgcn_mfma_f32_16x16x32_bf16(al[fr], bh[fc], acc[fr][fc], 0, 0, 0);
            }
        if (step < 11) {
            writeS(buf ^ 1);                 // other buffer: no read hazard
            __syncthreads();                 // one barrier per step
            buf ^= 1;
        }
    }

    // ---- direct fragment epilogue (L2 absorbs scatter) ----
    if (sec == 1) {
#pragma unroll
        for (int fr = 0; fr < 2; ++fr)
#pragma unroll
            for (int fc = 0; fc < 3; ++fc) {
                int m0  = wrb + fr * 16 + ksub * 4;
                int col = half * 96 + wcb + fc * 16 + r15;
                f32x4 v = acc[fr][fc];
#pragma unroll
                for (int q = 0; q < 4; ++q)
                    Zv[(size_t)(bm + m0 + q) * CC + col] = v[q];
            }
    } else {
        float* D = (sec == 0) ? ZTk : ZTr;
#pragma unroll
        for (int fr = 0; fr < 2; ++fr)
#pragma unroll
            for (int fc = 0; fc < 3; ++fc) {
                int m0  = wrb + fr * 16 + ksub * 4;
                int col = half * 96 + wcb + fc * 16 + r15;
                f32x4 v = acc[fr][fc];
                *(float4*)(D + (size_t)col * 8192 + bm + m0) = make_float4(v[0], v[1], v[2], v[3]);
            }
    }
}

// ---------------- GEMM2 (MFMA): out = P @ Wo; A read straight from PT (f32) ----
__global__ __launch_bounds__(256, 2) void k_gemm2_mfma(
        const float* __restrict__ PT,
        const unsigned short* __restrict__ WoTH, const unsigned short* __restrict__ WoTL,
        float* __restrict__ out) {
    __shared__ unsigned short sAh[64 * APAD], sAl[64 * APAD];
    __shared__ unsigned short sBh[64 * APAD], sBl[64 * APAD];
    const int tid  = threadIdx.x;
    const int w    = tid >> 6;
    const int lane = tid & 63;
    const int bn   = blockIdx.x * 64;
    const int bm   = blockIdx.y * 64;

    const int akk = tid >> 3;               // 0..31 (k row)
    const int am8 = (tid & 7) * 8;          // 0..56 (m chunk)
    const int bcol = tid >> 2;              // 0..63
    const int bkc  = (tid & 3) * 8;

    f32x4 acc[2][2];
#pragma unroll
    for (int i = 0; i < 2; ++i)
#pragma unroll
        for (int j = 0; j < 2; ++j) acc[i][j] = f32x4{0.f, 0.f, 0.f, 0.f};

    float4 p0, p1;
    uint4 rbh, rbl;
    auto loadAB = [&](int k0) {
        const float* pa = PT + (size_t)(k0 + akk) * 8192 + bm + am8;
        p0 = *(const float4*)pa;
        p1 = *(const float4*)(pa + 4);
        size_t o = (size_t)(bn + bcol) * CC + k0 + bkc;
        rbh = *(const uint4*)(WoTH + o);
        rbl = *(const uint4*)(WoTL + o);
    };
    auto writeS = [&]() {
        float fa[8] = {p0.x, p0.y, p0.z, p0.w, p1.x, p1.y, p1.z, p1.w};
#pragma unroll
        for (int j = 0; j < 8; ++j) {
            unsigned short h = f2bf(fa[j]);
            sAh[(am8 + j) * APAD + akk] = h;
            sAl[(am8 + j) * APAD + akk] = f2bf(fa[j] - bf2f(h));
        }
        *(uint4*)&sBh[bcol * APAD + bkc] = rbh;
        *(uint4*)&sBl[bcol * APAD + bkc] = rbl;
    };

    const int wrb = (w >> 1) * 32;
    const int wcb = (w & 1) * 32;
    const int r15 = lane & 15, ksub = lane >> 4;
    const int pc8 = ksub * 8;

    loadAB(0);
    for (int step = 0; step < 6; ++step) {
        __syncthreads();
        writeS();
        __syncthreads();
        if (step < 5) loadAB((step + 1) * 32);
        bf16x8 ah[2], al[2], bh[2], bl[2];
#pragma unroll
        for (int f = 0; f < 2; ++f) {
            int ra = (wrb + f * 16 + r15) * APAD + pc8;
            ah[f] = *(const bf16x8*)&sAh[ra];
            al[f] = *(const bf16x8*)&sAl[ra];
            int rb = (wcb + f * 16 + r15) * APAD + pc8;
            bh[f] = *(const bf16x8*)&sBh[rb];
            bl[f] = *(const bf16x8*)&sBl[rb];
        }
#pragma unroll
        for (int fr = 0; fr < 2; ++fr)
#pragma unroll
            for (int fc = 0; fc < 2; ++fc) {
                acc[fr][fc] = __builtin_amdgcn_mfma_f32_16x16x32_bf16(ah[fr], bh[fc], acc[fr][fc], 0, 0, 0);
                acc[fr][fc] = __builtin_amdgcn_mfma_f32_16x16x32_bf16(ah[fr], bl[fc], acc[fr][fc], 0, 0, 0);
                acc[fr][fc] = __builtin_amdgcn_mfma_f32_16x16x32_bf16(al[fr], bh[fc], acc[fr][fc], 0, 0, 0);
            }
    }

#pragma unroll
    for (int fr = 0; fr < 2; ++fr)
#pragma unroll
        for (int fc = 0; fc < 2; ++fc) {
            int m0  = wrb + fr * 16 + ksub * 4;
            int col = bn + wcb + fc * 16 + r15;
            f32x4 v = acc[fr][fc];
#pragma unroll
            for (int q = 0; q < 4; ++q)
                out[(size_t)(bm + m0 + q) * CC + col] = v[q];
        }
}

// ---------------- fused band_est + ada_peak (RMW into pixel-major Zv) -------
__global__ __launch_bounds__(192) void k_bandpeak(const float* __restrict__ x,
                                                  const float* __restrict__ cvw,
                                                  const float* __restrict__ cvb,
                                                  const float* __restrict__ bns_v,
                                                  const float* __restrict__ bnb_v,
                                                  const float* __restrict__ chw,
                                                  const float* __restrict__ chb,
                                                  const float* __restrict__ bns_h,
                                                  const float* __restrict__ bnb_h,
                                                  float* __restrict__ Zv) {
    int pixg = blockIdx.x;
    int b   = pixg >> 12;
    int pix = pixg & 4095;
    int i = pix >> 6, j = pix & 63;
    int c = threadIdx.x;
    size_t xbase = (size_t)b * TLEN * CC;

    float sv0 = 0.f, sv1 = 0.f, sh0 = 0.f, sh1 = 0.f;
#pragma unroll
    for (int t = 0; t < 7; ++t) {
        int ii = i + t - 3;
        if (ii >= 0 && ii < 64) {
            float xv = x[xbase + (size_t)(ii * 64 + j) * CC + c];
            sv0 = fmaf(xv, cvw[(0 * CC + c) * 7 + t], sv0);
            sv1 = fmaf(xv, cvw[(1 * CC + c) * 7 + t], sv1);
        }
        int jj = j + t - 3;
        if (jj >= 0 && jj < 64) {
            float xh = x[xbase + (size_t)(i * 64 + jj) * CC + c];
            sh0 = fmaf(xh, chw[(0 * CC + c) * 7 + t], sh0);
            sh1 = fmaf(xh, chw[(1 * CC + c) * 7 + t], sh1);
        }
    }
    __shared__ float red[4][CC];
    __shared__ float gsh[4];
    red[0][c] = sv0; red[1][c] = sv1; red[2][c] = sh0; red[3][c] = sh1;
    __syncthreads();
    if (c < 64) {
#pragma unroll
        for (int r = 0; r < 4; ++r) {
            float v = red[r][c] + red[r][c + 64] + red[r][c + 128];
            v += __shfl_xor(v, 32);
            v += __shfl_xor(v, 16);
            v += __shfl_xor(v, 8);
            v += __shfl_xor(v, 4);
            v += __shfl_xor(v, 2);
            v += __shfl_xor(v, 1);
            if (c == 0) {
                const float inv = 0.9999950000374997f;    // 1/sqrt(1+1e-5)
                float bias, sc, sh;
                if (r < 2) { bias = cvb[r];     sc = bns_v[r];     sh = bnb_v[r]; }
                else       { bias = chb[r - 2]; sc = bns_h[r - 2]; sh = bnb_h[r - 2]; }
                float g = (v + bias) * (sc * inv) + sh;
                gsh[r] = 2.0f / (1.0f + expf(-g));        // sigmoid * (GB_MAX-1)
            }
        }
    }
    __syncthreads();

    __shared__ int   l_lt[16], l_rb[16];
    __shared__ float l_glt[16], l_grb[16];
    if (c < 16) {
        int n = c, blk = n >> 2;
        float mx = (blk == 0) ? -gsh[0] : (blk == 2) ? gsh[1] : 0.0f;
        float my = (blk == 1) ?  gsh[3] : (blk == 3) ? -gsh[2] : 0.0f;
        float px = (float)(i + PADC) + PRF_X[n] + mx;
        float py = (float)(j + PADC) + PRF_Y[n] + my;
        float flx = floorf(px), fly = floorf(py);
        float qltx = fminf(fmaxf(flx, 0.f), 67.f);
        float qlty = fminf(fmaxf(fly, 0.f), 67.f);
        float qrbx = fminf(fmaxf(flx + 1.f, 0.f), 67.f);
        float qrby = fminf(fmaxf(fly + 1.f, 0.f), 67.f);
        float pxc = fminf(fmaxf(px, 0.f), 67.f);
        float pyc = fminf(fmaxf(py, 0.f), 67.f);
        float glt = (1.f + (qltx - pxc)) * (1.f + (qlty - pyc));
        float grb = (1.f - (qrbx - pxc)) * (1.f - (qrby - pyc));
        int sltx = min(max((int)qltx - PADC, 0), 63);
        int slty = min(max((int)qlty - PADC, 0), 63);
        int srbx = min(max((int)qrbx - PADC, 0), 63);
        int srby = min(max((int)qrby - PADC, 0), 63);
        l_lt[n] = sltx * 64 + slty;
        l_rb[n] = srbx * 64 + srby;
        l_glt[n] = glt;
        l_grb[n] = grb;
    }
    __syncthreads();

    float acc = 0.f;
#pragma unroll
    for (int n = 0; n < 16; ++n) {
        acc = fmaf(l_glt[n], x[xbase + (size_t)l_lt[n] * CC + c], acc);
        acc = fmaf(l_grb[n], x[xbase + (size_t)l_rb[n] * CC + c], acc);
    }
    float peak = x[xbase + (size_t)pix * CC + c] - acc * 0.0625f;
    Zv[((size_t)b * TLEN + pix) * CC + c] += peak;
}

// ---------------- transpose v: Zv[8192][192] -> ZTv[192][8192] ----------------
__global__ __launch_bounds__(256) void k_transv(const float* __restrict__ Zv,
                                                float* __restrict__ ZTv) {
    __shared__ float tile[64][65];
    int tid = threadIdx.x;
    int rb = (blockIdx.x & 127) * 64;
    int cb = (blockIdx.x >> 7) * 64;
    int tr  = tid >> 4;
    int tc4 = (tid & 15) * 4;
#pragma unroll
    for (int q = 0; q < 4; ++q) {
        int r = tr + q * 16;
        float4 v = *(const float4*)(Zv + (size_t)(rb + r) * CC + cb + tc4);
        *(float4*)&tile[r][tc4] = v;
    }
    __syncthreads();
#pragma unroll
    for (int q = 0; q < 4; ++q) {
        int ccol = tr + q * 16;
        float4 o = {tile[tc4 + 0][ccol], tile[tc4 + 1][ccol],
                    tile[tc4 + 2][ccol], tile[tc4 + 3][ccol]};
        *(float4*)(ZTv + (size_t)(cb + ccol) * 8192 + rb + tc4) = o;
    }
}

// ---------------- bi_wkv: chunked associative scan, fully staged I/O -------
__global__ __launch_bounds__(256) void k_wkv2(const float* __restrict__ ZT,
                                              float* __restrict__ PT,
                                              const float* __restrict__ sd,
                                              const float* __restrict__ sf) {
    const int NTH = 256, CH = 16;
    int c = blockIdx.x % CC;
    int b = blockIdx.x / CC;
    const float w = sd[c] * (1.0f / 4096.0f);
    const float u = sf[c] * (1.0f / 4096.0f);

    __shared__ float buf[16 * WPAD];
    __shared__ float s_m[NTH], s_a[NTH], s_b[NTH], s_L[NTH];

    int tid = threadIdx.x;
    size_t base = (size_t)c * 8192 + (size_t)b * TLEN;

    float kr[CH], vr[CH], rr[CH];

    auto coopLoad = [&](const float* src) {
#pragma unroll
        for (int i = 0; i < 4; ++i) {
            int g = i * 1024 + tid * 4;
            float4 v = *(const float4*)(src + g);
            int jj0 = g & 15;
            int tp  = g >> 4;
            buf[(jj0 + 0) * WPAD + tp] = v.x;
            buf[(jj0 + 1) * WPAD + tp] = v.y;
            buf[(jj0 + 2) * WPAD + tp] = v.z;
            buf[(jj0 + 3) * WPAD + tp] = v.w;
        }
    };
    auto chunkRead = [&](float* dst) {
#pragma unroll
        for (int jj = 0; jj < CH; ++jj) dst[jj] = buf[jj * WPAD + tid];
    };

    coopLoad(ZT + base);                                __syncthreads();
    chunkRead(kr);                                      __syncthreads();
    coopLoad(ZT + (size_t)CC * 8192 + base);            __syncthreads();
    chunkRead(vr);                                      __syncthreads();
    coopLoad(ZT + (size_t)2 * CC * 8192 + base);        __syncthreads();
    chunkRead(rr);                                      __syncthreads();

    // ---- forward local chunk summary
    float m = -1e38f, a = 0.f, bb = 0.f;
#pragma unroll
    for (int jj = 0; jj < CH; ++jj) {
        float kt = kr[jj], vt = vr[jj];
        float m2 = fmaxf(m - w, kt);
        float e1 = expf(m - w - m2);
        float e2 = expf(kt - m2);
        a = e1 * a + e2;
        bb = e1 * bb + e2 * vt;
        m = m2;
    }
    s_m[tid] = m; s_a[tid] = a; s_b[tid] = bb; s_L[tid] = (float)CH;
    float L = (float)CH;
    for (int d = 1; d < NTH; d <<= 1) {
        __syncthreads();
        float pm = 0, pa = 0, pb = 0, pL = 0;
        bool has = (tid >= d);
        if (has) { pm = s_m[tid - d]; pa = s_a[tid - d]; pb = s_b[tid - d]; pL = s_L[tid - d]; }
        __syncthreads();
        if (has) {
            float pdec = pm - L * w;
            float m2 = fmaxf(pdec, m);
            float e1 = expf(pdec - m2);
            float e2 = expf(m - m2);
            a  = e1 * pa + e2 * a;
            bb = e1 * pb + e2 * bb;
            m = m2; L += pL;
            s_m[tid] = m; s_a[tid] = a; s_b[tid] = bb; s_L[tid] = L;
        }
    }
    __syncthreads();
    float fm = -1e38f, fa = 0.f, fb = 0.f;
    if (tid > 0) { fm = s_m[tid - 1]; fa = s_a[tid - 1]; fb = s_b[tid - 1]; }
    __syncthreads();

    // ---- backward local chunk summary
    m = -1e38f; a = 0.f; bb = 0.f;
#pragma unroll
    for (int jj = CH - 1; jj >= 0; --jj) {
        float kt = kr[jj], vt = vr[jj];
        float m2 = fmaxf(m - w, kt);
        float e1 = expf(m - w - m2);
        float e2 = expf(kt - m2);
        a = e1 * a + e2;
        bb = e1 * bb + e2 * vt;
        m = m2;
    }
    s_m[tid] = m; s_a[tid] = a; s_b[tid] = bb; s_L[tid] = (float)CH;
    L = (float)CH;
    for (int d = 1; d < NTH; d <<= 1) {
        __syncthreads();
        float pm = 0, pa = 0, pb = 0, pL = 0;
        bool has = (tid + d) < NTH;
        if (has) { pm = s_m[tid + d]; pa = s_a[tid + d]; pb = s_b[tid + d]; pL = s_L[tid + d]; }
        __syncthreads();
        if (has) {
            float pdec = pm - L * w;
            float m2 = fmaxf(m, pdec);
            float e1 = expf(m - m2);
            float e2 = expf(pdec - m2);
            a  = e1 * a + e2 * pa;
            bb = e1 * bb + e2 * pb;
            m = m2; L += pL;
            s_m[tid] = m; s_a[tid] = a; s_b[tid] = bb; s_L[tid] = L;
        }
    }
    __syncthreads();
    float bm2 = -1e38f, ba = 0.f, bbv = 0.f;
    if (tid < NTH - 1) { bm2 = s_m[tid + 1]; ba = s_a[tid + 1]; bbv = s_b[tid + 1]; }
    __syncthreads();

    // ---- backward re-scan
    float em[CH], ea[CH], eb[CH];
    m = bm2; a = ba; bb = bbv;
#pragma unroll
    for (int jj = CH - 1; jj >= 0; --jj) {
        em[jj] = m; ea[jj] = a; eb[jj] = bb;
        float kt = kr[jj], vt = vr[jj];
        float m2 = fmaxf(m - w, kt);
        float e1 = expf(m - w - m2);
        float e2 = expf(kt - m2);
        a = e1 * a + e2;
        bb = e1 * bb + e2 * vt;
        m = m2;
    }

    // ---- forward re-scan + combine; y staged into buf, then coalesced store
    m = fm; a = fa; bb = fb;
#pragma unroll
    for (int jj = 0; jj < CH; ++jj) {
        float kt = kr[jj], vt = vr[jj];
        float ms = u + kt;
        float M = fmaxf(fmaxf(m, em[jj]), ms);
        float ef  = expf(m - M);
        float ebk = expf(em[jj] - M);
        float es  = expf(ms - M);
        float num = ef * bb + ebk * eb[jj] + es * vt;
        float den = ef * a + ebk * ea[jj] + es;
        float y = num / den;
        float sr = 1.0f / (1.0f + expf(-rr[jj]));
        buf[jj * WPAD + tid] = sr * y;
        float m2 = fmaxf(m - w, kt);
        float e1 = expf(m - w - m2);
        float e2 = expf(kt - m2);
        a = e1 * a + e2;
        bb = e1 * bb + e2 * vt;
        m = m2;
    }
    __syncthreads();
#pragma unroll
    for (int i = 0; i < 4; ++i) {
        int g = i * 1024 + tid * 4;
        int jj0 = g & 15;
        int tp  = g >> 4;
        float4 o = {buf[(jj0 + 0) * WPAD + tp], buf[(jj0 + 1) * WPAD + tp],
                    buf[(jj0 + 2) * WPAD + tp], buf[(jj0 + 3) * WPAD + tp]};
        *(float4*)(PT + base + g) = o;
    }
}

extern "C" void kernel_launch(void* const* d_in, const int* in_sizes, int n_in,
                              void* d_out, int out_size, void* d_ws, size_t ws_size,
                              hipStream_t stream) {
    const float* x     = (const float*)d_in[0];
    const float* mix_k = (const float*)d_in[3];
    const float* mix_v = (const float*)d_in[4];
    const float* mix_r = (const float*)d_in[5];
    const float* Wk    = (const float*)d_in[6];
    const float* Wv    = (const float*)d_in[7];
    const float* Wr    = (const float*)d_in[8];
    const float* Wo    = (const float*)d_in[9];
    const float* sd    = (const float*)d_in[10];
    const float* sf    = (const float*)d_in[11];
    const float* cvw   = (const float*)d_in[12];
    const float* cvb   = (const float*)d_in[13];
    const float* bns_v = (const float*)d_in[14];
    const float* bnb_v = (const float*)d_in[15];
    const float* chw   = (const float*)d_in[16];
    const float* chb   = (const float*)d_in[17];
    const float* bns_h = (const float*)d_in[18];
    const float* bnb_h = (const float*)d_in[19];
    float* out = (float*)d_out;
    char* W = (char*)d_ws;

    // byte-offset workspace plan (26.2 MB, previously proven available):
    float*          Zv   = (float*)(W + 0);            // [8192][192] f32 (later PT)
    float*          ZTk  = (float*)(W + 6291456);      // [192][8192] f32 planes
    float*          ZTv  = (float*)(W + 12582912);
    float*          ZTr  = (float*)(W + 18874368);
    float*          PT   = Zv;                          // Zv dead after transv
    unsigned short* WTH  = (unsigned short*)(W + 25165824);
    unsigned short* WTL  = (unsigned short*)(W + 25608192);
    unsigned short* WoTH = (unsigned short*)(W + 26050560);
    unsigned short* WoTL = (unsigned short*)(W + 26124288);

    k_wcat_t<<<864, 256, 0, stream>>>(Wk, Wv, Wr, mix_k, mix_v, mix_r, WTH, WTL);
    k_prep_wo<<<144, 256, 0, stream>>>(Wo, WoTH, WoTL);
    k_gemm1_mfma<<<dim3(6, 128), 256, 0, stream>>>(x, WTH, WTL, ZTk, Zv, ZTr);
    k_bandpeak<<<8192, 192, 0, stream>>>(x, cvw, cvb, bns_v, bnb_v, chw, chb, bns_h, bnb_h, Zv);
    k_transv<<<384, 256, 0, stream>>>(Zv, ZTv);
    k_wkv2<<<384, 256, 0, stream>>>(ZTk, PT, sd, sf);
    k_gemm2_mfma<<<dim3(3, 128), 256, 0, stream>>>(PT, WoTH, WoTL, out);
}